// Round 5
// baseline (1402.546 us; speedup 1.0000x reference)
//
#include <hip/hip_runtime.h>

#define NN 100000
#define EE 1600000
#define DD 32
#define CC 2
#define NLAYERS 4
#define GG 512

#define BSH 9                         // log2(nodes per dst-bucket)
#define BW 512                        // nodes per dst-bucket
#define NBUK ((NN + BW - 1) / BW)     // 196
#define CAP 12288                     // per-bucket staging capacity (mean 8163)
#define CH 2048                       // edges per partition block
#define NPART ((EE + CH - 1) / CH)    // 782

// ---------------------------------------------------------------------------
// Phase 1: partition edges into NBUK dst-range buckets. LDS-staged so the
// global writes are coalesced runs. Packs (dst_local<<17 | src) into 4B
// (src < 2^17, dst_local < 2^9).
// ---------------------------------------------------------------------------
__global__ void part_kernel(const int* __restrict__ ei,
                            int* __restrict__ gcur,
                            unsigned* __restrict__ part) {
    __shared__ unsigned sorted[CH];        // 8 KB
    __shared__ unsigned char sbkt[CH];     // 2 KB
    __shared__ int cnt[NBUK], offs[NBUK], cur[NBUK], gbs[NBUK];

    const int tid = threadIdx.x;
    const int eb  = blockIdx.x * CH;
    const int nch = min(CH, EE - eb);

    for (int b = tid; b < NBUK; b += 256) cnt[b] = 0;
    __syncthreads();
    for (int i = tid; i < nch; i += 256) {
        int dn = ei[EE + eb + i];
        atomicAdd(&cnt[dn >> BSH], 1);
    }
    __syncthreads();
    if (tid == 0) {
        int o = 0;
        for (int b = 0; b < NBUK; ++b) { offs[b] = o; o += cnt[b]; }
    }
    __syncthreads();
    if (tid < NBUK) {
        cur[tid] = offs[tid];
        gbs[tid] = cnt[tid] ? atomicAdd(&gcur[tid], cnt[tid]) : 0;
    }
    __syncthreads();
    for (int i = tid; i < nch; i += 256) {
        int s  = ei[eb + i];
        int dn = ei[EE + eb + i];
        int b  = dn >> BSH;
        unsigned pk = ((unsigned)(dn & (BW - 1)) << 17) | (unsigned)s;
        int p = atomicAdd(&cur[b], 1);
        sorted[p] = pk;
        sbkt[p]   = (unsigned char)b;
    }
    __syncthreads();
    for (int i = tid; i < nch; i += 256) {
        int b = sbkt[i];
        part[(size_t)b * CAP + gbs[b] + (i - offs[b])] = sorted[i];
    }
}

// Phase 2: exclusive scan of 196 bucket counts (trivial).
__global__ void bscan_kernel(const int* __restrict__ gcur,
                             int* __restrict__ bbase,
                             int* __restrict__ row_ptr) {
    if (threadIdx.x == 0 && blockIdx.x == 0) {
        int o = 0;
        for (int b = 0; b < NBUK; ++b) { bbase[b] = o; o += gcur[b]; }
        row_ptr[NN] = EE;
    }
}

// ---------------------------------------------------------------------------
// Phase 3: per-bucket local CSR. Histogram + scan of 512 nodes in LDS; fill
// writes land in one contiguous ~32KB region -> L2-resident, no write amp.
// Also emits csr_dl[e] = dst local index within its 64-node layer block
// (buckets are 512-aligned, so local = dl & 63).
// ---------------------------------------------------------------------------
__global__ void lcsr_kernel(const unsigned* __restrict__ part,
                            const int* __restrict__ gcur,
                            const int* __restrict__ bbase,
                            int* __restrict__ row_ptr,
                            int* __restrict__ csr_src,
                            unsigned char* __restrict__ csr_dl) {
    __shared__ int hcnt[BW];
    __shared__ int a[2][BW];
    __shared__ int ccur[BW];
    const int t    = threadIdx.x;
    const int b    = blockIdx.x;
    const int cntb = gcur[b];
    const int base = bbase[b];
    const size_t pb = (size_t)b * CAP;

    hcnt[t] = 0;
    __syncthreads();
    for (int i = t; i < cntb; i += BW)
        atomicAdd(&hcnt[part[pb + i] >> 17], 1);
    __syncthreads();
    int x = hcnt[t];
    a[0][t] = x;
    __syncthreads();
    int cb = 0;
    for (int off = 1; off < BW; off <<= 1) {
        int v = a[cb][t];
        if (t >= off) v += a[cb][t - off];
        a[cb ^ 1][t] = v;
        cb ^= 1;
        __syncthreads();
    }
    const int excl = a[cb][t] - x;
    const int node = b * BW + t;
    if (node < NN) row_ptr[node] = base + excl;
    ccur[t] = excl;
    __syncthreads();
    for (int i = t; i < cntb; i += BW) {
        unsigned pk = part[pb + i];
        int dl  = pk >> 17;
        int pos = base + atomicAdd(&ccur[dl], 1);
        csr_src[pos] = (int)(pk & 0x1FFFFu);
        csr_dl[pos]  = (unsigned char)(dl & 63);
    }
}

// ---------------------------------------------------------------------------
// Fused GIN layer. Block = 64 nodes. Phase 1: the block's contiguous CSR edge
// range (~1024 edges) is split EVENLY across the 8 thread-groups; each group
// streams edges 16-at-a-time with 16 independent h-row gathers in flight,
// accumulating into zA via LDS atomics (bank = lane dim -> conflict-free).
// Phase 2: barrier-free MLP (weights in registers, z broadcast from LDS,
// z2 exchange within-wave) + fused pooled readout into LDS score image.
// ---------------------------------------------------------------------------
__global__ __launch_bounds__(256, 4) void layer_kernel(
    const float* __restrict__ h_in, float* __restrict__ h_out,
    const int* __restrict__ row_ptr, const int* __restrict__ csr_src,
    const unsigned char* __restrict__ csr_dl,
    const int* __restrict__ batch,
    const float* __restrict__ W1, const float* __restrict__ b1,
    const float* __restrict__ g1, const float* __restrict__ bt1,
    const float* __restrict__ W2, const float* __restrict__ b2,
    const float* __restrict__ g2, const float* __restrict__ bt2,
    const float* __restrict__ ng, const float* __restrict__ nb,
    const float* __restrict__ dWl, float* __restrict__ score) {
    __shared__ float sp[8 * DD];
    __shared__ float sdW[DD * CC];
    __shared__ float ss[GG * CC];      // 4 KB
    __shared__ float zA[64][DD];       // 8 KB
    __shared__ float z2loc[8][DD];     // 1 KB

    const int tid = threadIdx.x;
    const int j = tid >> 5;            // group 0..7
    const int d = tid & 31;

    float w1r[DD], w2r[DD];
    #pragma unroll
    for (int k = 0; k < DD; ++k) w1r[k] = W1[k * DD + d];
    #pragma unroll
    for (int k = 0; k < DD; ++k) w2r[k] = W2[k * DD + d];

    if (tid < DD) {
        sp[0 * DD + tid] = b1[tid];
        sp[1 * DD + tid] = g1[tid];
        sp[2 * DD + tid] = bt1[tid];
        sp[3 * DD + tid] = b2[tid];
        sp[4 * DD + tid] = g2[tid];
        sp[5 * DD + tid] = bt2[tid];
        sp[6 * DD + tid] = ng[tid];
        sp[7 * DD + tid] = nb[tid];
    }
    if (tid < DD * CC) sdW[tid] = dWl[tid];
    for (int i = tid; i < GG * CC; i += 256) ss[i] = 0.f;

    const float invs = 1.0f / sqrtf(1.001f);   // BN: mean=0, var=1, eps=1e-3
    const int base = blockIdx.x * 64;

    // self-term init of zA (also zeroes pad rows)
    #pragma unroll
    for (int s = 0; s < 8; ++s) {
        const int local = j * 8 + s;
        const int n = base + local;
        zA[local][d] = (n < NN) ? h_in[(size_t)n * DD + d] : 0.f;
    }
    __syncthreads();

    // phase 1: flattened, load-balanced gather with 16 loads in flight
    {
        const int nEnd = (base + 64 < NN) ? (base + 64) : NN;
        const int E0 = row_ptr[base];
        const int E1 = row_ptr[nEnd];
        const int cnt = E1 - E0;
        const int chunk = (cnt + 7) >> 3;
        int g0 = E0 + j * chunk;
        int g1 = g0 + chunk;
        if (g0 > E1) g0 = E1;
        if (g1 > E1) g1 = E1;

        int e = g0;
        for (; e + 16 <= g1; e += 16) {
            int idx[16];
            #pragma unroll
            for (int i = 0; i < 16; ++i) idx[i] = csr_src[e + i];
            int dl[16];
            #pragma unroll
            for (int i = 0; i < 16; ++i) dl[i] = csr_dl[e + i];
            float v[16];
            #pragma unroll
            for (int i = 0; i < 16; ++i) v[i] = h_in[(size_t)idx[i] * DD + d];
            #pragma unroll
            for (int i = 0; i < 16; ++i) atomicAdd(&zA[dl[i]][d], v[i]);
        }
        for (; e < g1; ++e)
            atomicAdd(&zA[csr_dl[e]][d], h_in[(size_t)csr_src[e] * DD + d]);
    }
    __syncthreads();

    // phase 2: MLP + fused pool (no barriers; z2loc stays within one wave)
    for (int s = 0; s < 8; ++s) {
        const int local = j * 8 + s;
        const int n = base + local;
        if (n >= NN) break;                 // uniform within the 32-lane group

        float a1 = sp[0 * DD + d];
        #pragma unroll
        for (int kk = 0; kk < DD; kk += 4) {
            const float4 zv = *reinterpret_cast<const float4*>(&zA[local][kk]);
            a1 += zv.x * w1r[kk] + zv.y * w1r[kk + 1] +
                  zv.z * w1r[kk + 2] + zv.w * w1r[kk + 3];
        }
        float v = fmaxf(a1 * (sp[1 * DD + d] * invs) + sp[2 * DD + d], 0.f);
        z2loc[j][d] = v;                    // within-wave exchange (in-order LDS)

        float a2 = sp[3 * DD + d];
        #pragma unroll
        for (int kk = 0; kk < DD; kk += 4) {
            const float4 zv = *reinterpret_cast<const float4*>(&z2loc[j][kk]);
            a2 += zv.x * w2r[kk] + zv.y * w2r[kk + 1] +
                  zv.z * w2r[kk + 2] + zv.w * w2r[kk + 3];
        }
        float w = fmaxf(a2 * (sp[4 * DD + d] * invs) + sp[5 * DD + d], 0.f);
        w = fmaxf(w * (sp[6 * DD + d] * invs) + sp[7 * DD + d], 0.f);
        h_out[(size_t)n * DD + d] = w;

        float p0 = w * sdW[d * CC + 0];
        float p1 = w * sdW[d * CC + 1];
        #pragma unroll
        for (int off = 16; off > 0; off >>= 1) {
            p0 += __shfl_xor(p0, off, 32);
            p1 += __shfl_xor(p1, off, 32);
        }
        if (d == 0) {
            int g = batch[n];
            atomicAdd(&ss[g * CC + 0], p0);
            atomicAdd(&ss[g * CC + 1], p1);
        }
    }
    __syncthreads();

    for (int i = tid; i < GG * CC; i += 256) {
        float v = ss[i];
        if (v != 0.f) atomicAdd(&score[i], v);
    }
}

// ---------------------------------------------------------------------------
// Pool + readout for hidden level 0 (raw embeddings)
// ---------------------------------------------------------------------------
__global__ void pool_kernel(const float* __restrict__ h,
                            const int* __restrict__ batch,
                            const float* __restrict__ Wd,
                            float* __restrict__ score) {
    __shared__ float ss[GG * CC];
    __shared__ float sW[DD * CC];
    const int tid = threadIdx.x;
    for (int i = tid; i < GG * CC; i += 256) ss[i] = 0.f;
    if (tid < DD * CC) sW[tid] = Wd[tid];
    __syncthreads();

    const int d = tid & 31;
    const int grp = tid >> 5;
    const int n0 = blockIdx.x * 512;
    const int n1 = (n0 + 512 < NN) ? (n0 + 512) : NN;

    for (int n = n0 + grp; n < n1; n += 8) {
        float v = h[(size_t)n * DD + d];
        float p0 = v * sW[d * CC + 0];
        float p1 = v * sW[d * CC + 1];
        #pragma unroll
        for (int off = 16; off > 0; off >>= 1) {
            p0 += __shfl_xor(p0, off, 32);
            p1 += __shfl_xor(p1, off, 32);
        }
        if (d == 0) {
            int g = batch[n];
            atomicAdd(&ss[g * CC + 0], p0);
            atomicAdd(&ss[g * CC + 1], p1);
        }
    }
    __syncthreads();

    for (int i = tid; i < GG * CC; i += 256) {
        float v = ss[i];
        if (v != 0.f) atomicAdd(&score[i], v);
    }
}

__global__ void softmax_kernel(const float* __restrict__ score,
                               const float* __restrict__ db,
                               float* __restrict__ out) {
    int g = blockIdx.x * blockDim.x + threadIdx.x;
    if (g >= GG) return;
    float bs0 = 0.f, bs1 = 0.f;
    #pragma unroll
    for (int i = 0; i <= NLAYERS; ++i) {
        bs0 += db[i * CC + 0];
        bs1 += db[i * CC + 1];
    }
    float s0 = score[g * CC + 0] + bs0;
    float s1 = score[g * CC + 1] + bs1;
    float m = fmaxf(s0, s1);
    float e0 = expf(s0 - m), e1 = expf(s1 - m);
    float inv = 1.f / (e0 + e1);
    out[g * CC + 0] = e0 * inv;
    out[g * CC + 1] = e1 * inv;
}

extern "C" void kernel_launch(void* const* d_in, const int* in_sizes, int n_in,
                              void* d_out, int out_size, void* d_ws, size_t ws_size,
                              hipStream_t stream) {
    (void)in_sizes; (void)n_in; (void)out_size; (void)ws_size;

    const float* node_emb = (const float*)d_in[0];
    const int*   ei       = (const int*)d_in[1];
    const int*   batch    = (const int*)d_in[2];
    const float* W1       = (const float*)d_in[3];
    const float* b1       = (const float*)d_in[4];
    const float* g1       = (const float*)d_in[5];
    const float* bt1      = (const float*)d_in[6];
    const float* W2       = (const float*)d_in[7];
    const float* b2       = (const float*)d_in[8];
    const float* g2       = (const float*)d_in[9];
    const float* bt2      = (const float*)d_in[10];
    const float* ng       = (const float*)d_in[11];
    const float* nb       = (const float*)d_in[12];
    const float* dW       = (const float*)d_in[13];
    const float* db       = (const float*)d_in[14];
    float* out = (float*)d_out;

    // workspace layout (part[] aliases hB: hB is first written by layer 2,
    // long after lcsr has consumed part[])
    float* hA      = (float*)d_ws;                    // [NN][DD] 12.8MB
    float* hB      = hA + (size_t)NN * DD;            // [NN][DD] 12.8MB
    unsigned* part = (unsigned*)hB;                   // [NBUK][CAP] 9.6MB alias
    float* score   = hB + (size_t)NN * DD;            // [GG][CC]
    int* row_ptr   = (int*)(score + GG * CC);         // [NN+1]
    int* csr_src   = row_ptr + NN + 2;                // [EE] 6.4MB
    int* gcur      = csr_src + EE;                    // [256]
    int* bbase     = gcur + 256;                      // [256]
    unsigned char* csr_dl = (unsigned char*)(bbase + 256);  // [EE] 1.6MB

    hipMemsetAsync(gcur, 0, 256 * sizeof(int), stream);
    hipMemsetAsync(score, 0, GG * CC * sizeof(float), stream);

    // CSR build (cache-local)
    part_kernel<<<NPART, 256, 0, stream>>>(ei, gcur, part);
    bscan_kernel<<<1, 64, 0, stream>>>(gcur, bbase, row_ptr);
    lcsr_kernel<<<NBUK, BW, 0, stream>>>(part, gcur, bbase, row_ptr, csr_src, csr_dl);

    // hidden level 0 readout on raw embeddings
    pool_kernel<<<(NN + 511) / 512, 256, 0, stream>>>(node_emb, batch, dW, score);

    const int layerGrid = (NN + 63) / 64;             // 1563
    const float* cur_in = node_emb;
    float* bufs[2] = {hA, hB};
    for (int i = 0; i < NLAYERS; ++i) {
        float* o = bufs[i & 1];
        layer_kernel<<<layerGrid, 256, 0, stream>>>(
            cur_in, o, row_ptr, csr_src, csr_dl, batch,
            W1 + (size_t)i * DD * DD, b1 + i * DD, g1 + i * DD, bt1 + i * DD,
            W2 + (size_t)i * DD * DD, b2 + i * DD, g2 + i * DD, bt2 + i * DD,
            ng + i * DD, nb + i * DD,
            dW + (size_t)(i + 1) * DD * CC, score);
        cur_in = o;
    }

    softmax_kernel<<<(GG + 255) / 256, 256, 0, stream>>>(score, db, out);
}

// Round 6
// 1396.183 us; speedup vs baseline: 1.0046x; 1.0046x over previous
//
#include <hip/hip_runtime.h>

#define NN 100000
#define EE 1600000
#define DD 32
#define CC 2
#define NLAYERS 4
#define GG 512

#define BSH 9                         // log2(nodes per dst-bucket)
#define BW 512                        // nodes per dst-bucket
#define NBUK ((NN + BW - 1) / BW)     // 196
#define CAP 12288                     // per-bucket staging capacity (mean 8163)
#define CH 2048                       // edges per partition block
#define NPART ((EE + CH - 1) / CH)    // 782

// ---------------------------------------------------------------------------
// Phase 1: partition edges into NBUK dst-range buckets. LDS-staged so the
// global writes are coalesced runs. Packs (dst_local<<17 | src) into 4B
// (src < 2^17, dst_local < 2^9).
// ---------------------------------------------------------------------------
__global__ void part_kernel(const int* __restrict__ ei,
                            int* __restrict__ gcur,
                            unsigned* __restrict__ part) {
    __shared__ unsigned sorted[CH];        // 8 KB
    __shared__ unsigned char sbkt[CH];     // 2 KB
    __shared__ int cnt[NBUK], offs[NBUK], cur[NBUK], gbs[NBUK];

    const int tid = threadIdx.x;
    const int eb  = blockIdx.x * CH;
    const int nch = min(CH, EE - eb);

    for (int b = tid; b < NBUK; b += 256) cnt[b] = 0;
    __syncthreads();
    for (int i = tid; i < nch; i += 256) {
        int dn = ei[EE + eb + i];
        atomicAdd(&cnt[dn >> BSH], 1);
    }
    __syncthreads();
    if (tid == 0) {
        int o = 0;
        for (int b = 0; b < NBUK; ++b) { offs[b] = o; o += cnt[b]; }
    }
    __syncthreads();
    if (tid < NBUK) {
        cur[tid] = offs[tid];
        gbs[tid] = cnt[tid] ? atomicAdd(&gcur[tid], cnt[tid]) : 0;
    }
    __syncthreads();
    for (int i = tid; i < nch; i += 256) {
        int s  = ei[eb + i];
        int dn = ei[EE + eb + i];
        int b  = dn >> BSH;
        unsigned pk = ((unsigned)(dn & (BW - 1)) << 17) | (unsigned)s;
        int p = atomicAdd(&cur[b], 1);
        sorted[p] = pk;
        sbkt[p]   = (unsigned char)b;
    }
    __syncthreads();
    for (int i = tid; i < nch; i += 256) {
        int b = sbkt[i];
        part[(size_t)b * CAP + gbs[b] + (i - offs[b])] = sorted[i];
    }
}

// Phase 2: exclusive scan of 196 bucket counts (trivial).
__global__ void bscan_kernel(const int* __restrict__ gcur,
                             int* __restrict__ bbase,
                             int* __restrict__ row_ptr) {
    if (threadIdx.x == 0 && blockIdx.x == 0) {
        int o = 0;
        for (int b = 0; b < NBUK; ++b) { bbase[b] = o; o += gcur[b]; }
        row_ptr[NN] = EE;
    }
}

// ---------------------------------------------------------------------------
// Phase 3: per-bucket local CSR. Histogram + scan of 512 nodes in LDS; fill
// writes land in one contiguous ~32KB region -> L2-resident, no write amp.
// csr_packed[pos] = (dst%64)<<17 | src  (buckets 512-aligned, blocks 64-aligned)
// ---------------------------------------------------------------------------
__global__ void lcsr_kernel(const unsigned* __restrict__ part,
                            const int* __restrict__ gcur,
                            const int* __restrict__ bbase,
                            int* __restrict__ row_ptr,
                            unsigned* __restrict__ csr_packed) {
    __shared__ int hcnt[BW];
    __shared__ int a[2][BW];
    __shared__ int ccur[BW];
    const int t    = threadIdx.x;
    const int b    = blockIdx.x;
    const int cntb = gcur[b];
    const int base = bbase[b];
    const size_t pb = (size_t)b * CAP;

    hcnt[t] = 0;
    __syncthreads();
    for (int i = t; i < cntb; i += BW)
        atomicAdd(&hcnt[part[pb + i] >> 17], 1);
    __syncthreads();
    int x = hcnt[t];
    a[0][t] = x;
    __syncthreads();
    int cb = 0;
    for (int off = 1; off < BW; off <<= 1) {
        int v = a[cb][t];
        if (t >= off) v += a[cb][t - off];
        a[cb ^ 1][t] = v;
        cb ^= 1;
        __syncthreads();
    }
    const int excl = a[cb][t] - x;
    const int node = b * BW + t;
    if (node < NN) row_ptr[node] = base + excl;
    ccur[t] = excl;
    __syncthreads();
    for (int i = t; i < cntb; i += BW) {
        unsigned pk = part[pb + i];
        int dl  = pk >> 17;
        int pos = base + atomicAdd(&ccur[dl], 1);
        csr_packed[pos] = ((unsigned)(dl & 63) << 17) | (pk & 0x1FFFFu);
    }
}

// ---------------------------------------------------------------------------
// Fused GIN layer. Block = 64 nodes. Phase 1: the block's contiguous CSR edge
// range (~1024 edges) is split EVENLY across the 8 thread-groups; each group
// streams edges 16-at-a-time with 16 independent h-row gathers in flight,
// accumulating into zA via LDS atomics (bank = lane dim -> conflict-free).
// Packed (dl<<17|src) halves the live index registers. NO launch-bounds
// min-waves (r5's VGPR cap at 64 caused scratch spills: WRITE 12.5->28MB).
// Phase 2: barrier-free MLP + fused pooled readout into LDS score image.
// ---------------------------------------------------------------------------
__global__ __launch_bounds__(256) void layer_kernel(
    const float* __restrict__ h_in, float* __restrict__ h_out,
    const int* __restrict__ row_ptr, const unsigned* __restrict__ csr_packed,
    const int* __restrict__ batch,
    const float* __restrict__ W1, const float* __restrict__ b1,
    const float* __restrict__ g1, const float* __restrict__ bt1,
    const float* __restrict__ W2, const float* __restrict__ b2,
    const float* __restrict__ g2, const float* __restrict__ bt2,
    const float* __restrict__ ng, const float* __restrict__ nb,
    const float* __restrict__ dWl, float* __restrict__ score) {
    __shared__ float sp[8 * DD];
    __shared__ float sdW[DD * CC];
    __shared__ float ss[GG * CC];      // 4 KB
    __shared__ float zA[64][DD];       // 8 KB
    __shared__ float z2loc[8][DD];     // 1 KB

    const int tid = threadIdx.x;
    const int j = tid >> 5;            // group 0..7
    const int d = tid & 31;

    if (tid < DD) {
        sp[0 * DD + tid] = b1[tid];
        sp[1 * DD + tid] = g1[tid];
        sp[2 * DD + tid] = bt1[tid];
        sp[3 * DD + tid] = b2[tid];
        sp[4 * DD + tid] = g2[tid];
        sp[5 * DD + tid] = bt2[tid];
        sp[6 * DD + tid] = ng[tid];
        sp[7 * DD + tid] = nb[tid];
    }
    if (tid < DD * CC) sdW[tid] = dWl[tid];
    for (int i = tid; i < GG * CC; i += 256) ss[i] = 0.f;

    const float invs = 1.0f / sqrtf(1.001f);   // BN: mean=0, var=1, eps=1e-3
    const int base = blockIdx.x * 64;

    // self-term init of zA (also zeroes pad rows)
    #pragma unroll
    for (int s = 0; s < 8; ++s) {
        const int local = j * 8 + s;
        const int n = base + local;
        zA[local][d] = (n < NN) ? h_in[(size_t)n * DD + d] : 0.f;
    }
    __syncthreads();

    // phase 1: flattened, load-balanced gather with 16 loads in flight
    {
        const int nEnd = (base + 64 < NN) ? (base + 64) : NN;
        const int E0 = row_ptr[base];
        const int E1 = row_ptr[nEnd];
        const int cnt = E1 - E0;
        const int chunk = (cnt + 7) >> 3;
        int g0 = E0 + j * chunk;
        int g1 = g0 + chunk;
        if (g0 > E1) g0 = E1;
        if (g1 > E1) g1 = E1;

        int e = g0;
        for (; e + 16 <= g1; e += 16) {
            unsigned pk[16];
            #pragma unroll
            for (int i = 0; i < 16; ++i) pk[i] = csr_packed[e + i];
            float v[16];
            #pragma unroll
            for (int i = 0; i < 16; ++i)
                v[i] = h_in[(size_t)(pk[i] & 0x1FFFFu) * DD + d];
            #pragma unroll
            for (int i = 0; i < 16; ++i)
                atomicAdd(&zA[pk[i] >> 17][d], v[i]);
        }
        for (; e < g1; ++e) {
            unsigned pk = csr_packed[e];
            atomicAdd(&zA[pk >> 17][d], h_in[(size_t)(pk & 0x1FFFFu) * DD + d]);
        }
    }
    __syncthreads();

    // phase 2: MLP + fused pool (no barriers; z2loc stays within one wave)
    for (int s = 0; s < 8; ++s) {
        const int local = j * 8 + s;
        const int n = base + local;
        if (n >= NN) break;                 // uniform within the 32-lane group

        float a1 = sp[0 * DD + d];
        #pragma unroll
        for (int kk = 0; kk < DD; kk += 4) {
            const float4 zv = *reinterpret_cast<const float4*>(&zA[local][kk]);
            a1 += zv.x * W1[(kk + 0) * DD + d] + zv.y * W1[(kk + 1) * DD + d] +
                  zv.z * W1[(kk + 2) * DD + d] + zv.w * W1[(kk + 3) * DD + d];
        }
        float v = fmaxf(a1 * (sp[1 * DD + d] * invs) + sp[2 * DD + d], 0.f);
        z2loc[j][d] = v;                    // within-wave exchange (in-order LDS)

        float a2 = sp[3 * DD + d];
        #pragma unroll
        for (int kk = 0; kk < DD; kk += 4) {
            const float4 zv = *reinterpret_cast<const float4*>(&z2loc[j][kk]);
            a2 += zv.x * W2[(kk + 0) * DD + d] + zv.y * W2[(kk + 1) * DD + d] +
                  zv.z * W2[(kk + 2) * DD + d] + zv.w * W2[(kk + 3) * DD + d];
        }
        float w = fmaxf(a2 * (sp[4 * DD + d] * invs) + sp[5 * DD + d], 0.f);
        w = fmaxf(w * (sp[6 * DD + d] * invs) + sp[7 * DD + d], 0.f);
        h_out[(size_t)n * DD + d] = w;

        float p0 = w * sdW[d * CC + 0];
        float p1 = w * sdW[d * CC + 1];
        #pragma unroll
        for (int off = 16; off > 0; off >>= 1) {
            p0 += __shfl_xor(p0, off, 32);
            p1 += __shfl_xor(p1, off, 32);
        }
        if (d == 0) {
            int g = batch[n];
            atomicAdd(&ss[g * CC + 0], p0);
            atomicAdd(&ss[g * CC + 1], p1);
        }
    }
    __syncthreads();

    for (int i = tid; i < GG * CC; i += 256) {
        float v = ss[i];
        if (v != 0.f) atomicAdd(&score[i], v);
    }
}

// ---------------------------------------------------------------------------
// Pool + readout for hidden level 0 (raw embeddings)
// ---------------------------------------------------------------------------
__global__ void pool_kernel(const float* __restrict__ h,
                            const int* __restrict__ batch,
                            const float* __restrict__ Wd,
                            float* __restrict__ score) {
    __shared__ float ss[GG * CC];
    __shared__ float sW[DD * CC];
    const int tid = threadIdx.x;
    for (int i = tid; i < GG * CC; i += 256) ss[i] = 0.f;
    if (tid < DD * CC) sW[tid] = Wd[tid];
    __syncthreads();

    const int d = tid & 31;
    const int grp = tid >> 5;
    const int n0 = blockIdx.x * 512;
    const int n1 = (n0 + 512 < NN) ? (n0 + 512) : NN;

    for (int n = n0 + grp; n < n1; n += 8) {
        float v = h[(size_t)n * DD + d];
        float p0 = v * sW[d * CC + 0];
        float p1 = v * sW[d * CC + 1];
        #pragma unroll
        for (int off = 16; off > 0; off >>= 1) {
            p0 += __shfl_xor(p0, off, 32);
            p1 += __shfl_xor(p1, off, 32);
        }
        if (d == 0) {
            int g = batch[n];
            atomicAdd(&ss[g * CC + 0], p0);
            atomicAdd(&ss[g * CC + 1], p1);
        }
    }
    __syncthreads();

    for (int i = tid; i < GG * CC; i += 256) {
        float v = ss[i];
        if (v != 0.f) atomicAdd(&score[i], v);
    }
}

__global__ void softmax_kernel(const float* __restrict__ score,
                               const float* __restrict__ db,
                               float* __restrict__ out) {
    int g = blockIdx.x * blockDim.x + threadIdx.x;
    if (g >= GG) return;
    float bs0 = 0.f, bs1 = 0.f;
    #pragma unroll
    for (int i = 0; i <= NLAYERS; ++i) {
        bs0 += db[i * CC + 0];
        bs1 += db[i * CC + 1];
    }
    float s0 = score[g * CC + 0] + bs0;
    float s1 = score[g * CC + 1] + bs1;
    float m = fmaxf(s0, s1);
    float e0 = expf(s0 - m), e1 = expf(s1 - m);
    float inv = 1.f / (e0 + e1);
    out[g * CC + 0] = e0 * inv;
    out[g * CC + 1] = e1 * inv;
}

extern "C" void kernel_launch(void* const* d_in, const int* in_sizes, int n_in,
                              void* d_out, int out_size, void* d_ws, size_t ws_size,
                              hipStream_t stream) {
    (void)in_sizes; (void)n_in; (void)out_size; (void)ws_size;

    const float* node_emb = (const float*)d_in[0];
    const int*   ei       = (const int*)d_in[1];
    const int*   batch    = (const int*)d_in[2];
    const float* W1       = (const float*)d_in[3];
    const float* b1       = (const float*)d_in[4];
    const float* g1       = (const float*)d_in[5];
    const float* bt1      = (const float*)d_in[6];
    const float* W2       = (const float*)d_in[7];
    const float* b2       = (const float*)d_in[8];
    const float* g2       = (const float*)d_in[9];
    const float* bt2      = (const float*)d_in[10];
    const float* ng       = (const float*)d_in[11];
    const float* nb       = (const float*)d_in[12];
    const float* dW       = (const float*)d_in[13];
    const float* db       = (const float*)d_in[14];
    float* out = (float*)d_out;

    // workspace layout (part[] aliases hB: hB is first written by layer 2,
    // long after lcsr has consumed part[])
    float* hA      = (float*)d_ws;                    // [NN][DD] 12.8MB
    float* hB      = hA + (size_t)NN * DD;            // [NN][DD] 12.8MB
    unsigned* part = (unsigned*)hB;                   // [NBUK][CAP] 9.6MB alias
    float* score   = hB + (size_t)NN * DD;            // [GG][CC]
    int* row_ptr   = (int*)(score + GG * CC);         // [NN+1]
    unsigned* csr_packed = (unsigned*)(row_ptr + NN + 2);  // [EE] 6.4MB
    int* gcur      = (int*)(csr_packed + EE);         // [256]
    int* bbase     = gcur + 256;                      // [256]

    hipMemsetAsync(gcur, 0, 256 * sizeof(int), stream);
    hipMemsetAsync(score, 0, GG * CC * sizeof(float), stream);

    // CSR build (cache-local)
    part_kernel<<<NPART, 256, 0, stream>>>(ei, gcur, part);
    bscan_kernel<<<1, 64, 0, stream>>>(gcur, bbase, row_ptr);
    lcsr_kernel<<<NBUK, BW, 0, stream>>>(part, gcur, bbase, row_ptr, csr_packed);

    // hidden level 0 readout on raw embeddings
    pool_kernel<<<(NN + 511) / 512, 256, 0, stream>>>(node_emb, batch, dW, score);

    const int layerGrid = (NN + 63) / 64;             // 1563
    const float* cur_in = node_emb;
    float* bufs[2] = {hA, hB};
    for (int i = 0; i < NLAYERS; ++i) {
        float* o = bufs[i & 1];
        layer_kernel<<<layerGrid, 256, 0, stream>>>(
            cur_in, o, row_ptr, csr_packed, batch,
            W1 + (size_t)i * DD * DD, b1 + i * DD, g1 + i * DD, bt1 + i * DD,
            W2 + (size_t)i * DD * DD, b2 + i * DD, g2 + i * DD, bt2 + i * DD,
            ng + i * DD, nb + i * DD,
            dW + (size_t)(i + 1) * DD * CC, score);
        cur_in = o;
    }

    softmax_kernel<<<(GG + 255) / 256, 256, 0, stream>>>(score, db, out);
}

// Round 7
// 444.247 us; speedup vs baseline: 3.1571x; 3.1428x over previous
//
#include <hip/hip_runtime.h>

#define NN 100000
#define EE 1600000
#define DD 32
#define CC 2
#define NLAYERS 4
#define GG 512

#define BSH 9                         // log2(nodes per dst-bucket)
#define BW 512                        // nodes per dst-bucket
#define NBUK ((NN + BW - 1) / BW)     // 196
#define CAP 12288                     // per-bucket staging capacity (mean 8163)
#define CH 2048                       // edges per partition block
#define NPART ((EE + CH - 1) / CH)    // 782

// ---------------------------------------------------------------------------
// Phase 1: partition edges into NBUK dst-range buckets. LDS-staged so the
// global writes are coalesced runs. Packs (dst_local<<17 | src) into 4B
// (src < 2^17, dst_local < 2^9).
// ---------------------------------------------------------------------------
__global__ void part_kernel(const int* __restrict__ ei,
                            int* __restrict__ gcur,
                            unsigned* __restrict__ part) {
    __shared__ unsigned sorted[CH];        // 8 KB
    __shared__ unsigned char sbkt[CH];     // 2 KB
    __shared__ int cnt[NBUK], offs[NBUK], cur[NBUK], gbs[NBUK];

    const int tid = threadIdx.x;
    const int eb  = blockIdx.x * CH;
    const int nch = min(CH, EE - eb);

    for (int b = tid; b < NBUK; b += 256) cnt[b] = 0;
    __syncthreads();
    for (int i = tid; i < nch; i += 256) {
        int dn = ei[EE + eb + i];
        atomicAdd(&cnt[dn >> BSH], 1);
    }
    __syncthreads();
    if (tid == 0) {
        int o = 0;
        for (int b = 0; b < NBUK; ++b) { offs[b] = o; o += cnt[b]; }
    }
    __syncthreads();
    if (tid < NBUK) {
        cur[tid] = offs[tid];
        gbs[tid] = cnt[tid] ? atomicAdd(&gcur[tid], cnt[tid]) : 0;
    }
    __syncthreads();
    for (int i = tid; i < nch; i += 256) {
        int s  = ei[eb + i];
        int dn = ei[EE + eb + i];
        int b  = dn >> BSH;
        unsigned pk = ((unsigned)(dn & (BW - 1)) << 17) | (unsigned)s;
        int p = atomicAdd(&cur[b], 1);
        sorted[p] = pk;
        sbkt[p]   = (unsigned char)b;
    }
    __syncthreads();
    for (int i = tid; i < nch; i += 256) {
        int b = sbkt[i];
        part[(size_t)b * CAP + gbs[b] + (i - offs[b])] = sorted[i];
    }
}

// Phase 2: exclusive scan of 196 bucket counts (trivial).
__global__ void bscan_kernel(const int* __restrict__ gcur,
                             int* __restrict__ bbase,
                             int* __restrict__ row_ptr) {
    if (threadIdx.x == 0 && blockIdx.x == 0) {
        int o = 0;
        for (int b = 0; b < NBUK; ++b) { bbase[b] = o; o += gcur[b]; }
        row_ptr[NN] = EE;
    }
}

// ---------------------------------------------------------------------------
// Phase 3: per-bucket local CSR. Histogram + scan of 512 nodes in LDS; fill
// writes land in one contiguous ~32KB region -> L2-resident, no write amp.
// csr_packed[pos] = (dst%64)<<17 | src  (dl kept for flexibility; gather masks)
// ---------------------------------------------------------------------------
__global__ void lcsr_kernel(const unsigned* __restrict__ part,
                            const int* __restrict__ gcur,
                            const int* __restrict__ bbase,
                            int* __restrict__ row_ptr,
                            unsigned* __restrict__ csr_packed) {
    __shared__ int hcnt[BW];
    __shared__ int a[2][BW];
    __shared__ int ccur[BW];
    const int t    = threadIdx.x;
    const int b    = blockIdx.x;
    const int cntb = gcur[b];
    const int base = bbase[b];
    const size_t pb = (size_t)b * CAP;

    hcnt[t] = 0;
    __syncthreads();
    for (int i = t; i < cntb; i += BW)
        atomicAdd(&hcnt[part[pb + i] >> 17], 1);
    __syncthreads();
    int x = hcnt[t];
    a[0][t] = x;
    __syncthreads();
    int cb = 0;
    for (int off = 1; off < BW; off <<= 1) {
        int v = a[cb][t];
        if (t >= off) v += a[cb][t - off];
        a[cb ^ 1][t] = v;
        cb ^= 1;
        __syncthreads();
    }
    const int excl = a[cb][t] - x;
    const int node = b * BW + t;
    if (node < NN) row_ptr[node] = base + excl;
    ccur[t] = excl;
    __syncthreads();
    for (int i = t; i < cntb; i += BW) {
        unsigned pk = part[pb + i];
        int dl  = pk >> 17;
        int pos = base + atomicAdd(&ccur[dl], 1);
        csr_packed[pos] = ((unsigned)(dl & 63) << 17) | (pk & 0x1FFFFu);
    }
}

// ---------------------------------------------------------------------------
// Fused GIN layer (r4 structure, deepened). Block = 64 nodes, 8 groups x 8
// nodes. Phase 1: per-node gather with REGISTER accumulator and a
// 16/8/4/scalar unroll ladder -> up to 16 independent h-row loads in flight
// per group (32 per wave). No LDS atomics (r5/r6: ds_add + reg-starved
// pipeline = 3.4x regression). ONE barrier. Phase 2: barrier-free MLP
// (W via global/L1, z broadcast from LDS, z2 exchange within-wave) + fused
// pooled readout into LDS score image.
// ---------------------------------------------------------------------------
__global__ __launch_bounds__(256) void layer_kernel(
    const float* __restrict__ h_in, float* __restrict__ h_out,
    const int* __restrict__ row_ptr, const unsigned* __restrict__ csr_packed,
    const int* __restrict__ batch,
    const float* __restrict__ W1, const float* __restrict__ b1,
    const float* __restrict__ g1, const float* __restrict__ bt1,
    const float* __restrict__ W2, const float* __restrict__ b2,
    const float* __restrict__ g2, const float* __restrict__ bt2,
    const float* __restrict__ ng, const float* __restrict__ nb,
    const float* __restrict__ dWl, float* __restrict__ score) {
    __shared__ float sp[8 * DD];
    __shared__ float sdW[DD * CC];
    __shared__ float ss[GG * CC];      // 4 KB
    __shared__ float zA[64][DD];       // 8 KB
    __shared__ float z2loc[8][DD];     // 1 KB

    const int tid = threadIdx.x;
    const int j = tid >> 5;            // group 0..7
    const int d = tid & 31;

    if (tid < DD) {
        sp[0 * DD + tid] = b1[tid];
        sp[1 * DD + tid] = g1[tid];
        sp[2 * DD + tid] = bt1[tid];
        sp[3 * DD + tid] = b2[tid];
        sp[4 * DD + tid] = g2[tid];
        sp[5 * DD + tid] = bt2[tid];
        sp[6 * DD + tid] = ng[tid];
        sp[7 * DD + tid] = nb[tid];
    }
    if (tid < DD * CC) sdW[tid] = dWl[tid];
    for (int i = tid; i < GG * CC; i += 256) ss[i] = 0.f;

    const float invs = 1.0f / sqrtf(1.001f);   // BN: mean=0, var=1, eps=1e-3
    const int base = blockIdx.x * 64;

    // phase 1: per-node gather, deep unroll ladder (16 loads in flight)
    for (int s = 0; s < 8; ++s) {
        const int local = j * 8 + s;
        const int n = base + local;
        if (n >= NN) break;                 // uniform within the 32-lane group
        float acc = h_in[(size_t)n * DD + d];
        int e = row_ptr[n];
        const int e1 = row_ptr[n + 1];
        for (; e + 16 <= e1; e += 16) {
            unsigned ix[16];
            #pragma unroll
            for (int i = 0; i < 16; ++i) ix[i] = csr_packed[e + i] & 0x1FFFFu;
            float v[16];
            #pragma unroll
            for (int i = 0; i < 16; ++i) v[i] = h_in[(size_t)ix[i] * DD + d];
            float t0 = ((v[0] + v[1]) + (v[2] + v[3])) +
                       ((v[4] + v[5]) + (v[6] + v[7]));
            float t1 = ((v[8] + v[9]) + (v[10] + v[11])) +
                       ((v[12] + v[13]) + (v[14] + v[15]));
            acc += t0 + t1;
        }
        if (e + 8 <= e1) {
            unsigned ix[8];
            #pragma unroll
            for (int i = 0; i < 8; ++i) ix[i] = csr_packed[e + i] & 0x1FFFFu;
            float v[8];
            #pragma unroll
            for (int i = 0; i < 8; ++i) v[i] = h_in[(size_t)ix[i] * DD + d];
            acc += ((v[0] + v[1]) + (v[2] + v[3])) +
                   ((v[4] + v[5]) + (v[6] + v[7]));
            e += 8;
        }
        if (e + 4 <= e1) {
            unsigned ix[4];
            #pragma unroll
            for (int i = 0; i < 4; ++i) ix[i] = csr_packed[e + i] & 0x1FFFFu;
            float v[4];
            #pragma unroll
            for (int i = 0; i < 4; ++i) v[i] = h_in[(size_t)ix[i] * DD + d];
            acc += (v[0] + v[1]) + (v[2] + v[3]);
            e += 4;
        }
        for (; e < e1; ++e)
            acc += h_in[(size_t)(csr_packed[e] & 0x1FFFFu) * DD + d];
        zA[local][d] = acc;
    }
    __syncthreads();

    // phase 2: MLP + fused pool (no barriers; z2loc stays within one wave)
    for (int s = 0; s < 8; ++s) {
        const int local = j * 8 + s;
        const int n = base + local;
        if (n >= NN) break;                 // uniform within the 32-lane group

        float a1 = sp[0 * DD + d];
        #pragma unroll
        for (int kk = 0; kk < DD; kk += 4) {
            const float4 zv = *reinterpret_cast<const float4*>(&zA[local][kk]);
            a1 += zv.x * W1[(kk + 0) * DD + d] + zv.y * W1[(kk + 1) * DD + d] +
                  zv.z * W1[(kk + 2) * DD + d] + zv.w * W1[(kk + 3) * DD + d];
        }
        float v = fmaxf(a1 * (sp[1 * DD + d] * invs) + sp[2 * DD + d], 0.f);
        z2loc[j][d] = v;                    // within-wave exchange (in-order LDS)

        float a2 = sp[3 * DD + d];
        #pragma unroll
        for (int kk = 0; kk < DD; kk += 4) {
            const float4 zv = *reinterpret_cast<const float4*>(&z2loc[j][kk]);
            a2 += zv.x * W2[(kk + 0) * DD + d] + zv.y * W2[(kk + 1) * DD + d] +
                  zv.z * W2[(kk + 2) * DD + d] + zv.w * W2[(kk + 3) * DD + d];
        }
        float w = fmaxf(a2 * (sp[4 * DD + d] * invs) + sp[5 * DD + d], 0.f);
        w = fmaxf(w * (sp[6 * DD + d] * invs) + sp[7 * DD + d], 0.f);
        h_out[(size_t)n * DD + d] = w;

        float p0 = w * sdW[d * CC + 0];
        float p1 = w * sdW[d * CC + 1];
        #pragma unroll
        for (int off = 16; off > 0; off >>= 1) {
            p0 += __shfl_xor(p0, off, 32);
            p1 += __shfl_xor(p1, off, 32);
        }
        if (d == 0) {
            int g = batch[n];
            atomicAdd(&ss[g * CC + 0], p0);
            atomicAdd(&ss[g * CC + 1], p1);
        }
    }
    __syncthreads();

    for (int i = tid; i < GG * CC; i += 256) {
        float v = ss[i];
        if (v != 0.f) atomicAdd(&score[i], v);
    }
}

// ---------------------------------------------------------------------------
// Pool + readout for hidden level 0 (raw embeddings)
// ---------------------------------------------------------------------------
__global__ void pool_kernel(const float* __restrict__ h,
                            const int* __restrict__ batch,
                            const float* __restrict__ Wd,
                            float* __restrict__ score) {
    __shared__ float ss[GG * CC];
    __shared__ float sW[DD * CC];
    const int tid = threadIdx.x;
    for (int i = tid; i < GG * CC; i += 256) ss[i] = 0.f;
    if (tid < DD * CC) sW[tid] = Wd[tid];
    __syncthreads();

    const int d = tid & 31;
    const int grp = tid >> 5;
    const int n0 = blockIdx.x * 512;
    const int n1 = (n0 + 512 < NN) ? (n0 + 512) : NN;

    for (int n = n0 + grp; n < n1; n += 8) {
        float v = h[(size_t)n * DD + d];
        float p0 = v * sW[d * CC + 0];
        float p1 = v * sW[d * CC + 1];
        #pragma unroll
        for (int off = 16; off > 0; off >>= 1) {
            p0 += __shfl_xor(p0, off, 32);
            p1 += __shfl_xor(p1, off, 32);
        }
        if (d == 0) {
            int g = batch[n];
            atomicAdd(&ss[g * CC + 0], p0);
            atomicAdd(&ss[g * CC + 1], p1);
        }
    }
    __syncthreads();

    for (int i = tid; i < GG * CC; i += 256) {
        float v = ss[i];
        if (v != 0.f) atomicAdd(&score[i], v);
    }
}

__global__ void softmax_kernel(const float* __restrict__ score,
                               const float* __restrict__ db,
                               float* __restrict__ out) {
    int g = blockIdx.x * blockDim.x + threadIdx.x;
    if (g >= GG) return;
    float bs0 = 0.f, bs1 = 0.f;
    #pragma unroll
    for (int i = 0; i <= NLAYERS; ++i) {
        bs0 += db[i * CC + 0];
        bs1 += db[i * CC + 1];
    }
    float s0 = score[g * CC + 0] + bs0;
    float s1 = score[g * CC + 1] + bs1;
    float m = fmaxf(s0, s1);
    float e0 = expf(s0 - m), e1 = expf(s1 - m);
    float inv = 1.f / (e0 + e1);
    out[g * CC + 0] = e0 * inv;
    out[g * CC + 1] = e1 * inv;
}

extern "C" void kernel_launch(void* const* d_in, const int* in_sizes, int n_in,
                              void* d_out, int out_size, void* d_ws, size_t ws_size,
                              hipStream_t stream) {
    (void)in_sizes; (void)n_in; (void)out_size; (void)ws_size;

    const float* node_emb = (const float*)d_in[0];
    const int*   ei       = (const int*)d_in[1];
    const int*   batch    = (const int*)d_in[2];
    const float* W1       = (const float*)d_in[3];
    const float* b1       = (const float*)d_in[4];
    const float* g1       = (const float*)d_in[5];
    const float* bt1      = (const float*)d_in[6];
    const float* W2       = (const float*)d_in[7];
    const float* b2       = (const float*)d_in[8];
    const float* g2       = (const float*)d_in[9];
    const float* bt2      = (const float*)d_in[10];
    const float* ng       = (const float*)d_in[11];
    const float* nb       = (const float*)d_in[12];
    const float* dW       = (const float*)d_in[13];
    const float* db       = (const float*)d_in[14];
    float* out = (float*)d_out;

    // workspace layout (part[] aliases hB: hB is first written by layer 2,
    // long after lcsr has consumed part[])
    float* hA      = (float*)d_ws;                    // [NN][DD] 12.8MB
    float* hB      = hA + (size_t)NN * DD;            // [NN][DD] 12.8MB
    unsigned* part = (unsigned*)hB;                   // [NBUK][CAP] 9.6MB alias
    float* score   = hB + (size_t)NN * DD;            // [GG][CC]
    int* row_ptr   = (int*)(score + GG * CC);         // [NN+1]
    unsigned* csr_packed = (unsigned*)(row_ptr + NN + 2);  // [EE] 6.4MB
    int* gcur      = (int*)(csr_packed + EE);         // [256]
    int* bbase     = gcur + 256;                      // [256]

    hipMemsetAsync(gcur, 0, 256 * sizeof(int), stream);
    hipMemsetAsync(score, 0, GG * CC * sizeof(float), stream);

    // CSR build (cache-local)
    part_kernel<<<NPART, 256, 0, stream>>>(ei, gcur, part);
    bscan_kernel<<<1, 64, 0, stream>>>(gcur, bbase, row_ptr);
    lcsr_kernel<<<NBUK, BW, 0, stream>>>(part, gcur, bbase, row_ptr, csr_packed);

    // hidden level 0 readout on raw embeddings
    pool_kernel<<<(NN + 511) / 512, 256, 0, stream>>>(node_emb, batch, dW, score);

    const int layerGrid = (NN + 63) / 64;             // 1563
    const float* cur_in = node_emb;
    float* bufs[2] = {hA, hB};
    for (int i = 0; i < NLAYERS; ++i) {
        float* o = bufs[i & 1];
        layer_kernel<<<layerGrid, 256, 0, stream>>>(
            cur_in, o, row_ptr, csr_packed, batch,
            W1 + (size_t)i * DD * DD, b1 + i * DD, g1 + i * DD, bt1 + i * DD,
            W2 + (size_t)i * DD * DD, b2 + i * DD, g2 + i * DD, bt2 + i * DD,
            ng + i * DD, nb + i * DD,
            dW + (size_t)(i + 1) * DD * CC, score);
        cur_in = o;
    }

    softmax_kernel<<<(GG + 255) / 256, 256, 0, stream>>>(score, db, out);
}